// Round 1
// baseline (940.026 us; speedup 1.0000x reference)
//
#include <hip/hip_runtime.h>
#include <math.h>

// ---------------------------------------------------------------------------
// Problem constants
// ---------------------------------------------------------------------------
#define E_ 256
#define HW_ 4096
#define BS_ 32
#define NTOK 864            // 27 * 32 rows of F
#define NQ 27               // NOBJ * K * K
#define STEPS_ 3
#define FHID 2048           // MLP*E
#define EPS_ 1e-5f

// workspace layout (float offsets)
#define WS_PART   ((size_t)0)         // 2048 * 256
#define WS_CTX    ((size_t)524288)    // 256
#define WS_QP     ((size_t)524544)    // 27*256
#define WS_KP     ((size_t)531456)    // 27*256
#define WS_VP     ((size_t)538368)    // 27*256
#define WS_F      ((size_t)545280)    // 864*256
#define WS_QPROJ  ((size_t)766464)    // 864*256
#define WS_ATTN   ((size_t)987648)    // 864*256
#define WS_H      ((size_t)1208832)   // 864*2048
#define WS_TMP2   ((size_t)2978304)   // 864*256
#define WS_WKB    ((size_t)3199488)   // 256*256 ushort (bf16)
#define WS_WVB    ((size_t)3232256)   // 256*256 ushort (bf16)

typedef short bf16x8 __attribute__((ext_vector_type(8)));
typedef float f32x4 __attribute__((ext_vector_type(4)));

__device__ __forceinline__ unsigned short f2bf(float f) {
    union { float f; unsigned u; } v; v.f = f;
    unsigned u = v.u;
    unsigned r = u + 0x7fffu + ((u >> 16) & 1u);   // round-to-nearest-even
    return (unsigned short)(r >> 16);
}
__device__ __forceinline__ float bf2f(unsigned short s) {
    union { unsigned u; float f; } v; v.u = ((unsigned)s) << 16;
    return v.f;
}

// ---------------------------------------------------------------------------
// Weight transpose + bf16 convert: wb[e][c] = bf16(W[c][e])
// grid 512 (which*256 + c-row), block 256
// ---------------------------------------------------------------------------
__global__ __launch_bounds__(256) void k_wconv(const float* __restrict__ wk,
                                               const float* __restrict__ wv,
                                               unsigned short* __restrict__ wkb,
                                               unsigned short* __restrict__ wvb) {
    int g = blockIdx.x;
    int which = g >> 8;
    int r = g & 255;               // c row
    int e = threadIdx.x;
    const float* W = which ? wv : wk;
    unsigned short* O = which ? wvb : wkb;
    O[(size_t)e * 256 + r] = f2bf(W[(size_t)r * 256 + e]);
}

// ---------------------------------------------------------------------------
// Phase A GEMM: per workgroup (b, p-tile 128, e-tile 128), interleaved X and V
// GEMMs over K=256 (8 stages of 32), bf16 MFMA 16x16x32. Writes per-wg partial
// sums of exp(X) (s) and exp(X)*V (t) over the 128 rows.
// grid 2048 = b(32) * ptile(32) * etile(2), block 256 (4 waves as 2x2)
// ---------------------------------------------------------------------------
__global__ __launch_bounds__(256) void pa_gemm(const float* __restrict__ f_e,
                                               const float* __restrict__ pos_emb,
                                               const unsigned short* __restrict__ wkb,
                                               const unsigned short* __restrict__ wvb,
                                               const float* __restrict__ bk,
                                               const float* __restrict__ bv,
                                               float* __restrict__ part) {
    __shared__ __align__(16) unsigned short lv[128 * 40];   // f_e tile bf16 [m][k]
    __shared__ __align__(16) unsigned short lx[128 * 40];   // (f_e+pos) bf16 [m][k]
    __shared__ __align__(16) unsigned short lbk[128 * 40];  // la_wk^T tile [n][k]
    __shared__ __align__(16) unsigned short lbv[128 * 40];  // la_wv^T tile [n][k]
    __shared__ float reds[2 * 128];
    __shared__ float redt[2 * 128];

    const int g  = blockIdx.x;
    const int et = g & 1;
    const int pt = (g >> 1) & 31;
    const int b  = g >> 6;
    const int p0 = pt * 128;
    const int e0 = et * 128;

    const int tid  = threadIdx.x;
    const int wave = tid >> 6;
    const int lane = tid & 63;
    const int quad = lane >> 4;
    const int l15  = lane & 15;
    const int wm = wave >> 1;   // m half (0/1)
    const int wn = wave & 1;    // n half (0/1)

    f32x4 accx[4][4], accv[4][4];
    const f32x4 zero4 = {0.f, 0.f, 0.f, 0.f};
#pragma unroll
    for (int i = 0; i < 4; ++i)
#pragma unroll
        for (int j = 0; j < 4; ++j) { accx[i][j] = zero4; accv[i][j] = zero4; }

    // staging thread mappings
    const int sk  = tid >> 3;          // 0..31 k index (f_e staging)
    const int sm0 = (tid & 7) << 4;    // m base 0..112
    const int pm  = tid >> 1;          // 0..127 row (pos / weights staging)
    const int pkh = (tid & 1) << 4;    // 0 or 16

    const float* feb = f_e + (size_t)b * (256 * 4096) + p0;

#pragma unroll 1
    for (int kt = 0; kt < 8; ++kt) {
        const int c0 = kt * 32;
        __syncthreads();   // previous iteration's fragment reads done

        // stage lv = bf16(f_e[b, c0+sk, p0+sm0 .. +15])
        {
            const float* src = feb + (size_t)(c0 + sk) * 4096 + sm0;
#pragma unroll
            for (int i = 0; i < 4; ++i) {
                float4 v = ((const float4*)src)[i];
                lv[(sm0 + 4 * i + 0) * 40 + sk] = f2bf(v.x);
                lv[(sm0 + 4 * i + 1) * 40 + sk] = f2bf(v.y);
                lv[(sm0 + 4 * i + 2) * 40 + sk] = f2bf(v.z);
                lv[(sm0 + 4 * i + 3) * 40 + sk] = f2bf(v.w);
            }
        }
        // stage weight tiles (already bf16, [n][k] contiguous)
        {
            const uint4* srck = (const uint4*)(wkb + ((size_t)(e0 + pm) * 256 + c0 + pkh));
            const uint4* srcv = (const uint4*)(wvb + ((size_t)(e0 + pm) * 256 + c0 + pkh));
            uint4* dk = (uint4*)&lbk[pm * 40 + pkh];
            uint4* dv = (uint4*)&lbv[pm * 40 + pkh];
            dk[0] = srck[0]; dk[1] = srck[1];
            dv[0] = srcv[0]; dv[1] = srcv[1];
        }
        __syncthreads();   // lv ready

        // stage lx = bf16(f_e + pos)
        {
            const float* psrc = pos_emb + ((size_t)(p0 + pm) * 32 + b) * 256 + c0 + pkh;
            union { uint4 v[2]; unsigned short s[16]; } tb, ob;
            const uint4* lsrc = (const uint4*)&lv[pm * 40 + pkh];
            tb.v[0] = lsrc[0]; tb.v[1] = lsrc[1];
#pragma unroll
            for (int i = 0; i < 4; ++i) {
                float4 pv = ((const float4*)psrc)[i];
                ob.s[4 * i + 0] = f2bf(bf2f(tb.s[4 * i + 0]) + pv.x);
                ob.s[4 * i + 1] = f2bf(bf2f(tb.s[4 * i + 1]) + pv.y);
                ob.s[4 * i + 2] = f2bf(bf2f(tb.s[4 * i + 2]) + pv.z);
                ob.s[4 * i + 3] = f2bf(bf2f(tb.s[4 * i + 3]) + pv.w);
            }
            uint4* ldst = (uint4*)&lx[pm * 40 + pkh];
            ldst[0] = ob.v[0]; ldst[1] = ob.v[1];
        }
        __syncthreads();   // lx, lbk, lbv ready

        bf16x8 av[4], ax[4], fk[4], fv[4];
#pragma unroll
        for (int ms = 0; ms < 4; ++ms) {
            int row = wm * 64 + ms * 16 + l15;
            av[ms] = *(const bf16x8*)&lv[row * 40 + quad * 8];
            ax[ms] = *(const bf16x8*)&lx[row * 40 + quad * 8];
        }
#pragma unroll
        for (int ns = 0; ns < 4; ++ns) {
            int row = wn * 64 + ns * 16 + l15;
            fk[ns] = *(const bf16x8*)&lbk[row * 40 + quad * 8];
            fv[ns] = *(const bf16x8*)&lbv[row * 40 + quad * 8];
        }
#pragma unroll
        for (int ms = 0; ms < 4; ++ms)
#pragma unroll
            for (int ns = 0; ns < 4; ++ns) {
                accx[ms][ns] = __builtin_amdgcn_mfma_f32_16x16x32_bf16(ax[ms], fk[ns], accx[ms][ns], 0, 0, 0);
                accv[ms][ns] = __builtin_amdgcn_mfma_f32_16x16x32_bf16(av[ms], fv[ns], accv[ms][ns], 0, 0, 0);
            }
    }
    __syncthreads();

    // epilogue: s = sum_rows exp(X + bk), t = sum_rows exp(X + bk) * (V + bv)
#pragma unroll
    for (int ns = 0; ns < 4; ++ns) {
        int nloc = wn * 64 + ns * 16 + l15;
        float bkv = bk[e0 + nloc];
        float bvv = bv[e0 + nloc];
        float ps = 0.f, pt_ = 0.f;
#pragma unroll
        for (int ms = 0; ms < 4; ++ms)
#pragma unroll
            for (int r = 0; r < 4; ++r) {
                float ex = __expf(accx[ms][ns][r] + bkv);
                float vv = accv[ms][ns][r] + bvv;
                ps += ex;
                pt_ += ex * vv;
            }
        ps  += __shfl_xor(ps, 16);  ps  += __shfl_xor(ps, 32);
        pt_ += __shfl_xor(pt_, 16); pt_ += __shfl_xor(pt_, 32);
        if (lane < 16) { reds[wm * 128 + nloc] = ps; redt[wm * 128 + nloc] = pt_; }
    }
    __syncthreads();
    if (tid < 128) {
        float s = reds[tid] + reds[128 + tid];
        float t = redt[tid] + redt[128 + tid];
        part[(size_t)g * 256 + tid] = s;
        part[(size_t)g * 256 + 128 + tid] = t;
    }
}

// ---------------------------------------------------------------------------
// Reduce partials -> context[e] = T/S. grid 256 (one per e), block 256.
// ---------------------------------------------------------------------------
__global__ __launch_bounds__(256) void pa_reduce(const float* __restrict__ part,
                                                 float* __restrict__ ctx) {
    int e = blockIdx.x, tid = threadIdx.x;
    int et = e >> 7, n = e & 127;
    float s = 0.f, t = 0.f;
#pragma unroll
    for (int j = 0; j < 4; ++j) {
        int q = tid * 4 + j;                       // 0..1023 (b,ptile) combos
        const float* p = part + (size_t)(q * 2 + et) * 256 + n;
        s += p[0];
        t += p[128];
    }
    int wave = tid >> 6, lane = tid & 63;
#pragma unroll
    for (int o = 1; o < 64; o <<= 1) { s += __shfl_xor(s, o); t += __shfl_xor(t, o); }
    __shared__ float rs[4], rt[4];
    if (lane == 0) { rs[wave] = s; rt[wave] = t; }
    __syncthreads();
    if (tid == 0) {
        float S = rs[0] + rs[1] + rs[2] + rs[3];
        float T = rt[0] + rt[1] + rt[2] + rt[3];
        ctx[e] = T / S;
    }
}

// ---------------------------------------------------------------------------
// Query positional encoding qp[27][256]. grid 27, block 256.
// ---------------------------------------------------------------------------
__global__ __launch_bounds__(256) void k_qpos(float* __restrict__ qp) {
    int n = blockIdx.x, e = threadIdx.x;
    int q9 = n % 9;
    int y = q9 / 3, x = q9 % 3;
    float pos; int idx;
    if (e < 128) { pos = (float)(y + 1); idx = e; }
    else         { pos = (float)(x + 1); idx = e - 128; }
    int j = idx >> 1;
    // 10000^(-j/64)
    float inv = expf(-(float)j * 0.14391156831212787f);
    float arg = pos * inv;
    qp[(size_t)n * 256 + e] = (idx & 1) ? cosf(arg) : sinf(arg);
}

// ---------------------------------------------------------------------------
// kp/vp = shape_map @ mha_wk/wv + b (batch-independent). grid 54, block 256.
// ---------------------------------------------------------------------------
__global__ __launch_bounds__(256) void k_kvproj(const float* __restrict__ sm,
                                                const float* __restrict__ wk,
                                                const float* __restrict__ bk,
                                                const float* __restrict__ wv,
                                                const float* __restrict__ bv,
                                                float* __restrict__ kp,
                                                float* __restrict__ vp) {
    int g = blockIdx.x;
    int n = g % 27, which = g / 27;
    int e = threadIdx.x;
    const float* W = which ? wv : wk;
    const float* B = which ? bv : bk;
    float* O = which ? vp : kp;
    const float* row = sm + (size_t)n * 256;
    float acc = 0.f;
    for (int c = 0; c < 256; ++c) acc += row[c] * W[(size_t)c * 256 + e];
    O[(size_t)n * 256 + e] = acc + B[e];
}

// F0[r][e] = shape_map[r>>5][e]. grid 864, block 256.
__global__ __launch_bounds__(256) void k_finit(const float* __restrict__ sm,
                                               float* __restrict__ F) {
    int r = blockIdx.x, e = threadIdx.x;
    F[(size_t)r * 256 + e] = sm[(size_t)(r >> 5) * 256 + e];
}

// ---------------------------------------------------------------------------
// qproj = (F + qp) @ mha_wq + bq.  grid 108, block 256 (8 rows/block)
// ---------------------------------------------------------------------------
__global__ __launch_bounds__(256) void k_qproj(const float* __restrict__ F,
                                               const float* __restrict__ qp,
                                               const float* __restrict__ wq,
                                               const float* __restrict__ bq,
                                               float* __restrict__ out) {
    __shared__ float xin[8][256];
    int r0 = blockIdx.x * 8, e = threadIdx.x;
#pragma unroll
    for (int j = 0; j < 8; ++j) {
        int r = r0 + j;
        xin[j][e] = F[(size_t)r * 256 + e] + qp[(size_t)(r >> 5) * 256 + e];
    }
    __syncthreads();
    float acc[8] = {0.f, 0.f, 0.f, 0.f, 0.f, 0.f, 0.f, 0.f};
    for (int c = 0; c < 256; ++c) {
        float w = wq[(size_t)c * 256 + e];
#pragma unroll
        for (int j = 0; j < 8; ++j) acc[j] += xin[j][c] * w;
    }
    float bb = bq[e];
#pragma unroll
    for (int j = 0; j < 8; ++j) out[(size_t)(r0 + j) * 256 + e] = acc[j] + bb;
}

// ---------------------------------------------------------------------------
// MHA core per (b,h): scores, softmax over s, @vp. grid 256, block 64.
// ---------------------------------------------------------------------------
__global__ __launch_bounds__(64) void k_attn(const float* __restrict__ qproj,
                                             const float* __restrict__ kp,
                                             const float* __restrict__ vp,
                                             float* __restrict__ aout) {
    __shared__ float qs[27][32], ks[27][32], vs[27][32], S[27][28];
    int b = blockIdx.x >> 3, h = blockIdx.x & 7, t = threadIdx.x;
    for (int idx = t; idx < 864; idx += 64) {
        int l = idx >> 5, d = idx & 31;
        qs[l][d] = qproj[(size_t)(l * 32 + b) * 256 + h * 32 + d];
        ks[l][d] = kp[(size_t)l * 256 + h * 32 + d];
        vs[l][d] = vp[(size_t)l * 256 + h * 32 + d];
    }
    __syncthreads();
    for (int idx = t; idx < 729; idx += 64) {
        int l = idx / 27, s_ = idx - l * 27;
        float a = 0.f;
#pragma unroll
        for (int d = 0; d < 32; ++d) a += qs[l][d] * ks[s_][d];
        S[l][s_] = a * 0.17677669529663687f;   // 1/sqrt(32)
    }
    __syncthreads();
    if (t < 27) {
        float m = -1e30f;
        for (int s_ = 0; s_ < 27; ++s_) m = fmaxf(m, S[t][s_]);
        float sum = 0.f;
        for (int s_ = 0; s_ < 27; ++s_) { float p = __expf(S[t][s_] - m); S[t][s_] = p; sum += p; }
        float inv = 1.f / sum;
        for (int s_ = 0; s_ < 27; ++s_) S[t][s_] *= inv;
    }
    __syncthreads();
    for (int idx = t; idx < 864; idx += 64) {
        int l = idx >> 5, d = idx & 31;
        float o = 0.f;
#pragma unroll
        for (int s_ = 0; s_ < 27; ++s_) o += S[l][s_] * vs[s_][d];
        aout[(size_t)(l * 32 + b) * 256 + h * 32 + d] = o;
    }
}

// ---------------------------------------------------------------------------
// F = LN(F + attn@wo + bo). grid 108, block 256.
// ---------------------------------------------------------------------------
__global__ __launch_bounds__(256) void k_oproj_ln(const float* __restrict__ aout,
                                                  const float* __restrict__ wo,
                                                  const float* __restrict__ bo,
                                                  const float* __restrict__ g1,
                                                  const float* __restrict__ b1,
                                                  float* __restrict__ F) {
    __shared__ float xin[8][256];
    __shared__ float rbs[8][4], rbq[8][4];
    int r0 = blockIdx.x * 8, e = threadIdx.x;
    int wave = e >> 6, lane = e & 63;
#pragma unroll
    for (int j = 0; j < 8; ++j) xin[j][e] = aout[(size_t)(r0 + j) * 256 + e];
    __syncthreads();
    float acc[8] = {0.f, 0.f, 0.f, 0.f, 0.f, 0.f, 0.f, 0.f};
    for (int c = 0; c < 256; ++c) {
        float w = wo[(size_t)c * 256 + e];
#pragma unroll
        for (int j = 0; j < 8; ++j) acc[j] += xin[j][c] * w;
    }
    float bb = bo[e];
    float val[8];
#pragma unroll
    for (int j = 0; j < 8; ++j) {
        val[j] = F[(size_t)(r0 + j) * 256 + e] + acc[j] + bb;
        float s = val[j], q = val[j] * val[j];
#pragma unroll
        for (int o = 1; o < 64; o <<= 1) { s += __shfl_xor(s, o); q += __shfl_xor(q, o); }
        if (lane == 0) { rbs[j][wave] = s; rbq[j][wave] = q; }
    }
    __syncthreads();
    float ge = g1[e], be = b1[e];
#pragma unroll
    for (int j = 0; j < 8; ++j) {
        float s = rbs[j][0] + rbs[j][1] + rbs[j][2] + rbs[j][3];
        float q = rbq[j][0] + rbq[j][1] + rbq[j][2] + rbq[j][3];
        float mean = s * (1.f / 256.f);
        float var  = q * (1.f / 256.f) - mean * mean;
        F[(size_t)(r0 + j) * 256 + e] = (val[j] - mean) * rsqrtf(var + EPS_) * ge + be;
    }
}

// ---------------------------------------------------------------------------
// Linear attention + LN: q=softmax_row(((F+qp)@la_wq + bq)/16); F=LN(F+q*ctx)
// grid 108, block 256.
// ---------------------------------------------------------------------------
__global__ __launch_bounds__(256) void k_lattn_ln(float* __restrict__ F,
                                                  const float* __restrict__ qp,
                                                  const float* __restrict__ wq,
                                                  const float* __restrict__ bq,
                                                  const float* __restrict__ ctx,
                                                  const float* __restrict__ g2,
                                                  const float* __restrict__ b2) {
    __shared__ float xin[8][256];
    __shared__ float rA[8][4], rB[8][4];
    int r0 = blockIdx.x * 8, e = threadIdx.x;
    int wave = e >> 6, lane = e & 63;
    float fv[8];
#pragma unroll
    for (int j = 0; j < 8; ++j) {
        int r = r0 + j;
        fv[j] = F[(size_t)r * 256 + e];
        xin[j][e] = fv[j] + qp[(size_t)(r >> 5) * 256 + e];
    }
    __syncthreads();
    float acc[8] = {0.f, 0.f, 0.f, 0.f, 0.f, 0.f, 0.f, 0.f};
    for (int c = 0; c < 256; ++c) {
        float w = wq[(size_t)c * 256 + e];
#pragma unroll
        for (int j = 0; j < 8; ++j) acc[j] += xin[j][c] * w;
    }
    float bb = bq[e];
    float y[8];
#pragma unroll
    for (int j = 0; j < 8; ++j) {
        y[j] = (acc[j] + bb) * 0.0625f;
        float m = y[j];
#pragma unroll
        for (int o = 1; o < 64; o <<= 1) m = fmaxf(m, __shfl_xor(m, o));
        if (lane == 0) rA[j][wave] = m;
    }
    __syncthreads();
    float p[8];
#pragma unroll
    for (int j = 0; j < 8; ++j) {
        float m = fmaxf(fmaxf(rA[j][0], rA[j][1]), fmaxf(rA[j][2], rA[j][3]));
        p[j] = __expf(y[j] - m);
        float s = p[j];
#pragma unroll
        for (int o = 1; o < 64; o <<= 1) s += __shfl_xor(s, o);
        if (lane == 0) rB[j][wave] = s;
    }
    __syncthreads();
    float cx = ctx[e];
    float val[8];
#pragma unroll
    for (int j = 0; j < 8; ++j) {
        float s = rB[j][0] + rB[j][1] + rB[j][2] + rB[j][3];
        val[j] = fv[j] + (p[j] / s) * cx;
    }
    __syncthreads();
#pragma unroll
    for (int j = 0; j < 8; ++j) {
        float s = val[j], q = val[j] * val[j];
#pragma unroll
        for (int o = 1; o < 64; o <<= 1) { s += __shfl_xor(s, o); q += __shfl_xor(q, o); }
        if (lane == 0) { rA[j][wave] = s; rB[j][wave] = q; }
    }
    __syncthreads();
    float ge = g2[e], be = b2[e];
#pragma unroll
    for (int j = 0; j < 8; ++j) {
        float s = rA[j][0] + rA[j][1] + rA[j][2] + rA[j][3];
        float q = rB[j][0] + rB[j][1] + rB[j][2] + rB[j][3];
        float mean = s * (1.f / 256.f);
        float var  = q * (1.f / 256.f) - mean * mean;
        F[(size_t)(r0 + j) * 256 + e] = (val[j] - mean) * rsqrtf(var + EPS_) * ge + be;
    }
}

// ---------------------------------------------------------------------------
// FFN1: H = gelu(F @ w1 + b1). grid (108,4), block 256 (8 rows x 512 cols)
// ---------------------------------------------------------------------------
__global__ __launch_bounds__(256) void k_ffn1(const float* __restrict__ F,
                                              const float* __restrict__ w1,
                                              const float* __restrict__ b1,
                                              float* __restrict__ H) {
    __shared__ float xin[8][256];
    int r0 = blockIdx.x * 8, cg = blockIdx.y, e = threadIdx.x;
#pragma unroll
    for (int j = 0; j < 8; ++j) xin[j][e] = F[(size_t)(r0 + j) * 256 + e];
    __syncthreads();
    int c0 = cg * 512;
    float acc0[8] = {0.f, 0.f, 0.f, 0.f, 0.f, 0.f, 0.f, 0.f};
    float acc1[8] = {0.f, 0.f, 0.f, 0.f, 0.f, 0.f, 0.f, 0.f};
    for (int c = 0; c < 256; ++c) {
        float wA = w1[(size_t)c * 2048 + c0 + e];
        float wB = w1[(size_t)c * 2048 + c0 + 256 + e];
#pragma unroll
        for (int j = 0; j < 8; ++j) { acc0[j] += xin[j][c] * wA; acc1[j] += xin[j][c] * wB; }
    }
    float bA = b1[c0 + e], bB = b1[c0 + 256 + e];
#pragma unroll
    for (int j = 0; j < 8; ++j) {
        float h = acc0[j] + bA;
        H[(size_t)(r0 + j) * 2048 + c0 + e] = 0.5f * h * (1.f + erff(h * 0.70710678118654752f));
        h = acc1[j] + bB;
        H[(size_t)(r0 + j) * 2048 + c0 + 256 + e] = 0.5f * h * (1.f + erff(h * 0.70710678118654752f));
    }
}

// ---------------------------------------------------------------------------
// FFN2a: tmp2 += H[:, kc*512:+512] @ w2[kc*512:+512, :]. grid (108,4), block 256
// ---------------------------------------------------------------------------
__global__ __launch_bounds__(256) void k_ffn2a(const float* __restrict__ H,
                                               const float* __restrict__ w2,
                                               float* __restrict__ tmp2) {
    __shared__ float hin[8][512];
    int r0 = blockIdx.x * 8, kc = blockIdx.y, e = threadIdx.x;
#pragma unroll
    for (int j = 0; j < 8; ++j) {
        hin[j][e]       = H[(size_t)(r0 + j) * 2048 + kc * 512 + e];
        hin[j][256 + e] = H[(size_t)(r0 + j) * 2048 + kc * 512 + 256 + e];
    }
    __syncthreads();
    float acc[8] = {0.f, 0.f, 0.f, 0.f, 0.f, 0.f, 0.f, 0.f};
    for (int c = 0; c < 512; ++c) {
        float w = w2[(size_t)(kc * 512 + c) * 256 + e];
#pragma unroll
        for (int j = 0; j < 8; ++j) acc[j] += hin[j][c] * w;
    }
#pragma unroll
    for (int j = 0; j < 8; ++j) atomicAdd(&tmp2[(size_t)(r0 + j) * 256 + e], acc[j]);
}

// ---------------------------------------------------------------------------
// FFN2b: F = LN(F + tmp2 + b2); write proto to out. grid 864, block 256.
// ---------------------------------------------------------------------------
__global__ __launch_bounds__(256) void k_ffn2b(const float* __restrict__ tmp2,
                                               const float* __restrict__ b2,
                                               const float* __restrict__ g3,
                                               const float* __restrict__ b3,
                                               float* __restrict__ F,
                                               float* __restrict__ out,
                                               int step) {
    __shared__ float rs[4], rq[4];
    int r = blockIdx.x, e = threadIdx.x;
    int wave = e >> 6, lane = e & 63;
    float val = tmp2[(size_t)r * 256 + e] + b2[e] + F[(size_t)r * 256 + e];
    float s = val, q = val * val;
#pragma unroll
    for (int o = 1; o < 64; o <<= 1) { s += __shfl_xor(s, o); q += __shfl_xor(q, o); }
    if (lane == 0) { rs[wave] = s; rq[wave] = q; }
    __syncthreads();
    float S = rs[0] + rs[1] + rs[2] + rs[3];
    float Q = rq[0] + rq[1] + rq[2] + rq[3];
    float mean = S * (1.f / 256.f);
    float var  = Q * (1.f / 256.f) - mean * mean;
    float o = (val - mean) * rsqrtf(var + EPS_) * g3[e] + b3[e];
    F[(size_t)r * 256 + e] = o;
    out[((size_t)step * 864 + r) * 256 + e] = o;
}

// ---------------------------------------------------------------------------
extern "C" void kernel_launch(void* const* d_in, const int* in_sizes, int n_in,
                              void* d_out, int out_size, void* d_ws, size_t ws_size,
                              hipStream_t stream) {
    const float* f_e     = (const float*)d_in[0];
    const float* pos_emb = (const float*)d_in[1];
    // d_in[2] bboxes unused
    const float* sm      = (const float*)d_in[3];
    const float* mha_wq  = (const float*)d_in[4];
    const float* mha_bq  = (const float*)d_in[5];
    const float* mha_wk  = (const float*)d_in[6];
    const float* mha_bk  = (const float*)d_in[7];
    const float* mha_wv  = (const float*)d_in[8];
    const float* mha_bv  = (const float*)d_in[9];
    const float* mha_wo  = (const float*)d_in[10];
    const float* mha_bo  = (const float*)d_in[11];
    const float* la_wq   = (const float*)d_in[12];
    const float* la_bq   = (const float*)d_in[13];
    const float* la_wk   = (const float*)d_in[14];
    const float* la_bk   = (const float*)d_in[15];
    const float* la_wv   = (const float*)d_in[16];
    const float* la_bv   = (const float*)d_in[17];
    const float* ff_w1   = (const float*)d_in[18];
    const float* ff_b1   = (const float*)d_in[19];
    const float* ff_w2   = (const float*)d_in[20];
    const float* ff_b2   = (const float*)d_in[21];
    const float* n1_g    = (const float*)d_in[22];
    const float* n1_b    = (const float*)d_in[23];
    const float* n2_g    = (const float*)d_in[24];
    const float* n2_b    = (const float*)d_in[25];
    const float* n3_g    = (const float*)d_in[26];
    const float* n3_b    = (const float*)d_in[27];

    float* ws = (float*)d_ws;
    float* part  = ws + WS_PART;
    float* ctx   = ws + WS_CTX;
    float* qp    = ws + WS_QP;
    float* kp    = ws + WS_KP;
    float* vp    = ws + WS_VP;
    float* F     = ws + WS_F;
    float* qproj = ws + WS_QPROJ;
    float* attn  = ws + WS_ATTN;
    float* H     = ws + WS_H;
    float* tmp2  = ws + WS_TMP2;
    unsigned short* wkb = (unsigned short*)(ws + WS_WKB);
    unsigned short* wvb = (unsigned short*)(ws + WS_WVB);

    float* out = (float*)d_out;

    // setup
    k_wconv<<<512, 256, 0, stream>>>(la_wk, la_wv, wkb, wvb);
    k_qpos<<<27, 256, 0, stream>>>(qp);
    k_kvproj<<<54, 256, 0, stream>>>(sm, mha_wk, mha_bk, mha_wv, mha_bv, kp, vp);
    k_finit<<<864, 256, 0, stream>>>(sm, F);

    // phase A: context over image memory
    pa_gemm<<<2048, 256, 0, stream>>>(f_e, pos_emb, wkb, wvb, la_bk, la_bv, part);
    pa_reduce<<<256, 256, 0, stream>>>(part, ctx);

    // phase B: 3 decoder steps
    for (int s = 0; s < STEPS_; ++s) {
        k_qproj<<<108, 256, 0, stream>>>(F, qp, mha_wq, mha_bq, qproj);
        k_attn<<<256, 64, 0, stream>>>(qproj, kp, vp, attn);
        k_oproj_ln<<<108, 256, 0, stream>>>(attn, mha_wo, mha_bo, n1_g, n1_b, F);
        k_lattn_ln<<<108, 256, 0, stream>>>(F, qp, la_wq, la_bq, ctx, n2_g, n2_b);
        k_ffn1<<<dim3(108, 4), 256, 0, stream>>>(F, ff_w1, ff_b1, H);
        hipMemsetAsync(tmp2, 0, (size_t)864 * 256 * 4, stream);
        k_ffn2a<<<dim3(108, 4), 256, 0, stream>>>(H, ff_w2, tmp2);
        k_ffn2b<<<864, 256, 0, stream>>>(tmp2, ff_b2, n3_g, n3_b, F, out, s);
    }
}

// Round 2
// 805.030 us; speedup vs baseline: 1.1677x; 1.1677x over previous
//
#include <hip/hip_runtime.h>
#include <math.h>

// ---------------------------------------------------------------------------
// Problem constants
// ---------------------------------------------------------------------------
#define EPS_ 1e-5f

// workspace layout (float offsets)
#define WS_PART   ((size_t)0)         // 2048*256
#define WS_CTX    ((size_t)524288)    // 256
#define WS_QP     ((size_t)524544)    // 27*256
#define WS_KP     ((size_t)531456)    // 27*256
#define WS_VP     ((size_t)538368)    // 27*256
#define WS_F      ((size_t)545280)    // 864*256
#define WS_ATTN   ((size_t)766464)    // 864*256 (aout)
#define WS_H      ((size_t)987648)    // 864*2048 ushort = 884736 f32 slots
#define WS_WKB    ((size_t)1872384)   // 256*256 ushort (la_wk^T bf16)
#define WS_WVB    ((size_t)1905152)   // 256*256 ushort (la_wv^T bf16)
#define WS_WOT    ((size_t)1937920)   // 256*256 ushort (mha_wo^T bf16)
#define WS_LAQT   ((size_t)1970688)   // 256*256 ushort (la_wq^T bf16)
#define WS_W1T    ((size_t)2003456)   // 2048*256 ushort
#define WS_W2T    ((size_t)2265600)   // 256*2048 ushort
#define WS_MT     ((size_t)2527744)   // 8*32*256 ushort (wq@kp^T, scaled)
#define WS_VPT    ((size_t)2560512)   // 8*32*32 ushort
#define WS_CST    ((size_t)2564608)   // 256 f32

typedef short bf16x8 __attribute__((ext_vector_type(8)));
typedef float f32x4 __attribute__((ext_vector_type(4)));

__device__ __forceinline__ unsigned short f2bf(float f) {
    union { float f; unsigned u; } v; v.f = f;
    unsigned u = v.u;
    unsigned r = u + 0x7fffu + ((u >> 16) & 1u);   // RNE
    return (unsigned short)(r >> 16);
}
__device__ __forceinline__ float bf2f(unsigned short s) {
    union { unsigned u; float f; } v; v.u = ((unsigned)s) << 16;
    return v.f;
}
__device__ __forceinline__ bf16x8 cvt8(const float* p) {
    float4 u = ((const float4*)p)[0];
    float4 v = ((const float4*)p)[1];
    bf16x8 r;
    r[0] = (short)f2bf(u.x); r[1] = (short)f2bf(u.y);
    r[2] = (short)f2bf(u.z); r[3] = (short)f2bf(u.w);
    r[4] = (short)f2bf(v.x); r[5] = (short)f2bf(v.y);
    r[6] = (short)f2bf(v.z); r[7] = (short)f2bf(v.w);
    return r;
}
__device__ __forceinline__ bf16x8 cvt8sum(const float* p, const float* q) {
    float4 u = ((const float4*)p)[0];
    float4 v = ((const float4*)p)[1];
    float4 a = ((const float4*)q)[0];
    float4 b = ((const float4*)q)[1];
    bf16x8 r;
    r[0] = (short)f2bf(u.x + a.x); r[1] = (short)f2bf(u.y + a.y);
    r[2] = (short)f2bf(u.z + a.z); r[3] = (short)f2bf(u.w + a.w);
    r[4] = (short)f2bf(v.x + b.x); r[5] = (short)f2bf(v.y + b.y);
    r[6] = (short)f2bf(v.z + b.z); r[7] = (short)f2bf(v.w + b.w);
    return r;
}

// ---------------------------------------------------------------------------
// Setup: transpose weights to bf16 [n][k] layouts.
// grid 3328, block 256
// ---------------------------------------------------------------------------
__global__ __launch_bounds__(256) void k_trans(const float* __restrict__ la_wk,
                                               const float* __restrict__ la_wv,
                                               const float* __restrict__ mha_wo,
                                               const float* __restrict__ la_wq,
                                               const float* __restrict__ ff_w1,
                                               const float* __restrict__ ff_w2,
                                               unsigned short* __restrict__ wkb,
                                               unsigned short* __restrict__ wvb,
                                               unsigned short* __restrict__ woT,
                                               unsigned short* __restrict__ laqT,
                                               unsigned short* __restrict__ w1T,
                                               unsigned short* __restrict__ w2T) {
    int g = blockIdx.x, t = threadIdx.x;
    if (g < 1024) {
        int which = g >> 8, r = g & 255;
        const float* W = (which == 0) ? la_wk : (which == 1) ? la_wv : (which == 2) ? mha_wo : la_wq;
        unsigned short* O = (which == 0) ? wkb : (which == 1) ? wvb : (which == 2) ? woT : laqT;
        O[(size_t)t * 256 + r] = f2bf(W[(size_t)r * 256 + t]);
    } else if (g < 3072) {
        int n = g - 1024;
        w1T[(size_t)n * 256 + t] = f2bf(ff_w1[(size_t)t * 2048 + n]);
    } else {
        int n = g - 3072;
        for (int i = 0; i < 8; ++i) {
            int k = t + 256 * i;
            w2T[(size_t)n * 2048 + k] = f2bf(ff_w2[(size_t)k * 256 + n]);
        }
    }
}

// ---------------------------------------------------------------------------
// Phase A GEMM (UNCHANGED from passing round 1)
// ---------------------------------------------------------------------------
__global__ __launch_bounds__(256) void pa_gemm(const float* __restrict__ f_e,
                                               const float* __restrict__ pos_emb,
                                               const unsigned short* __restrict__ wkb,
                                               const unsigned short* __restrict__ wvb,
                                               const float* __restrict__ bk,
                                               const float* __restrict__ bv,
                                               float* __restrict__ part) {
    __shared__ __align__(16) unsigned short lv[128 * 40];
    __shared__ __align__(16) unsigned short lx[128 * 40];
    __shared__ __align__(16) unsigned short lbk[128 * 40];
    __shared__ __align__(16) unsigned short lbv[128 * 40];
    __shared__ float reds[2 * 128];
    __shared__ float redt[2 * 128];

    const int g  = blockIdx.x;
    const int et = g & 1;
    const int pt = (g >> 1) & 31;
    const int b  = g >> 6;
    const int p0 = pt * 128;
    const int e0 = et * 128;

    const int tid  = threadIdx.x;
    const int wave = tid >> 6;
    const int lane = tid & 63;
    const int quad = lane >> 4;
    const int l15  = lane & 15;
    const int wm = wave >> 1;
    const int wn = wave & 1;

    f32x4 accx[4][4], accv[4][4];
    const f32x4 zero4 = {0.f, 0.f, 0.f, 0.f};
#pragma unroll
    for (int i = 0; i < 4; ++i)
#pragma unroll
        for (int j = 0; j < 4; ++j) { accx[i][j] = zero4; accv[i][j] = zero4; }

    const int sk  = tid >> 3;
    const int sm0 = (tid & 7) << 4;
    const int pm  = tid >> 1;
    const int pkh = (tid & 1) << 4;

    const float* feb = f_e + (size_t)b * (256 * 4096) + p0;

#pragma unroll 1
    for (int kt = 0; kt < 8; ++kt) {
        const int c0 = kt * 32;
        __syncthreads();
        {
            const float* src = feb + (size_t)(c0 + sk) * 4096 + sm0;
#pragma unroll
            for (int i = 0; i < 4; ++i) {
                float4 v = ((const float4*)src)[i];
                lv[(sm0 + 4 * i + 0) * 40 + sk] = f2bf(v.x);
                lv[(sm0 + 4 * i + 1) * 40 + sk] = f2bf(v.y);
                lv[(sm0 + 4 * i + 2) * 40 + sk] = f2bf(v.z);
                lv[(sm0 + 4 * i + 3) * 40 + sk] = f2bf(v.w);
            }
        }
        {
            const uint4* srck = (const uint4*)(wkb + ((size_t)(e0 + pm) * 256 + c0 + pkh));
            const uint4* srcv = (const uint4*)(wvb + ((size_t)(e0 + pm) * 256 + c0 + pkh));
            uint4* dk = (uint4*)&lbk[pm * 40 + pkh];
            uint4* dv = (uint4*)&lbv[pm * 40 + pkh];
            dk[0] = srck[0]; dk[1] = srck[1];
            dv[0] = srcv[0]; dv[1] = srcv[1];
        }
        __syncthreads();
        {
            const float* psrc = pos_emb + ((size_t)(p0 + pm) * 32 + b) * 256 + c0 + pkh;
            union { uint4 v[2]; unsigned short s[16]; } tb, ob;
            const uint4* lsrc = (const uint4*)&lv[pm * 40 + pkh];
            tb.v[0] = lsrc[0]; tb.v[1] = lsrc[1];
#pragma unroll
            for (int i = 0; i < 4; ++i) {
                float4 pv = ((const float4*)psrc)[i];
                ob.s[4 * i + 0] = f2bf(bf2f(tb.s[4 * i + 0]) + pv.x);
                ob.s[4 * i + 1] = f2bf(bf2f(tb.s[4 * i + 1]) + pv.y);
                ob.s[4 * i + 2] = f2bf(bf2f(tb.s[4 * i + 2]) + pv.z);
                ob.s[4 * i + 3] = f2bf(bf2f(tb.s[4 * i + 3]) + pv.w);
            }
            uint4* ldst = (uint4*)&lx[pm * 40 + pkh];
            ldst[0] = ob.v[0]; ldst[1] = ob.v[1];
        }
        __syncthreads();

        bf16x8 av[4], ax[4], fk[4], fv[4];
#pragma unroll
        for (int ms = 0; ms < 4; ++ms) {
            int row = wm * 64 + ms * 16 + l15;
            av[ms] = *(const bf16x8*)&lv[row * 40 + quad * 8];
            ax[ms] = *(const bf16x8*)&lx[row * 40 + quad * 8];
        }
#pragma unroll
        for (int ns = 0; ns < 4; ++ns) {
            int row = wn * 64 + ns * 16 + l15;
            fk[ns] = *(const bf16x8*)&lbk[row * 40 + quad * 8];
            fv[ns] = *(const bf16x8*)&lbv[row * 40 + quad * 8];
        }
#pragma unroll
        for (int ms = 0; ms < 4; ++ms)
#pragma unroll
            for (int ns = 0; ns < 4; ++ns) {
                accx[ms][ns] = __builtin_amdgcn_mfma_f32_16x16x32_bf16(ax[ms], fk[ns], accx[ms][ns], 0, 0, 0);
                accv[ms][ns] = __builtin_amdgcn_mfma_f32_16x16x32_bf16(av[ms], fv[ns], accv[ms][ns], 0, 0, 0);
            }
    }
    __syncthreads();

#pragma unroll
    for (int ns = 0; ns < 4; ++ns) {
        int nloc = wn * 64 + ns * 16 + l15;
        float bkv = bk[e0 + nloc];
        float bvv = bv[e0 + nloc];
        float ps = 0.f, pt_ = 0.f;
#pragma unroll
        for (int ms = 0; ms < 4; ++ms)
#pragma unroll
            for (int r = 0; r < 4; ++r) {
                float ex = __expf(accx[ms][ns][r] + bkv);
                float vv = accv[ms][ns][r] + bvv;
                ps += ex;
                pt_ += ex * vv;
            }
        ps  += __shfl_xor(ps, 16);  ps  += __shfl_xor(ps, 32);
        pt_ += __shfl_xor(pt_, 16); pt_ += __shfl_xor(pt_, 32);
        if (lane < 16) { reds[wm * 128 + nloc] = ps; redt[wm * 128 + nloc] = pt_; }
    }
    __syncthreads();
    if (tid < 128) {
        float s = reds[tid] + reds[128 + tid];
        float t = redt[tid] + redt[128 + tid];
        part[(size_t)g * 256 + tid] = s;
        part[(size_t)g * 256 + 128 + tid] = t;
    }
}

__global__ __launch_bounds__(256) void pa_reduce(const float* __restrict__ part,
                                                 float* __restrict__ ctx) {
    int e = blockIdx.x, tid = threadIdx.x;
    int et = e >> 7, n = e & 127;
    float s = 0.f, t = 0.f;
#pragma unroll
    for (int j = 0; j < 4; ++j) {
        int q = tid * 4 + j;
        const float* p = part + (size_t)(q * 2 + et) * 256 + n;
        s += p[0];
        t += p[128];
    }
    int wave = tid >> 6, lane = tid & 63;
#pragma unroll
    for (int o = 1; o < 64; o <<= 1) { s += __shfl_xor(s, o); t += __shfl_xor(t, o); }
    __shared__ float rs[4], rt[4];
    if (lane == 0) { rs[wave] = s; rt[wave] = t; }
    __syncthreads();
    if (tid == 0) {
        float S = rs[0] + rs[1] + rs[2] + rs[3];
        float T = rt[0] + rt[1] + rt[2] + rt[3];
        ctx[e] = T / S;
    }
}

// ---------------------------------------------------------------------------
// Query positional encoding qp[27][256]. grid 27, block 256.
// ---------------------------------------------------------------------------
__global__ __launch_bounds__(256) void k_qpos(float* __restrict__ qp) {
    int n = blockIdx.x, e = threadIdx.x;
    int q9 = n % 9;
    int y = q9 / 3, x = q9 % 3;
    float pos; int idx;
    if (e < 128) { pos = (float)(y + 1); idx = e; }
    else         { pos = (float)(x + 1); idx = e - 128; }
    int j = idx >> 1;
    float inv = expf(-(float)j * 0.14391156831212787f);
    float arg = pos * inv;
    qp[(size_t)n * 256 + e] = (idx & 1) ? cosf(arg) : sinf(arg);
}

// kp/vp = shape_map @ mha_wk/wv + b. grid 54, block 256.
__global__ __launch_bounds__(256) void k_kvproj(const float* __restrict__ sm,
                                                const float* __restrict__ wk,
                                                const float* __restrict__ bk,
                                                const float* __restrict__ wv,
                                                const float* __restrict__ bv,
                                                float* __restrict__ kp,
                                                float* __restrict__ vp) {
    int g = blockIdx.x;
    int n = g % 27, which = g / 27;
    int e = threadIdx.x;
    const float* W = which ? wv : wk;
    const float* B = which ? bv : bk;
    float* O = which ? vp : kp;
    const float* row = sm + (size_t)n * 256;
    float acc = 0.f;
    for (int c = 0; c < 256; ++c) acc += row[c] * W[(size_t)c * 256 + e];
    O[(size_t)n * 256 + e] = acc + B[e];
}

// MT[h][s][c] = scale * sum_d wq[c][h*32+d]*kp[s][h*32+d]; cst[h][s] likewise for bq.
// grid 256 (h*32+s), block 256 (c)
__global__ __launch_bounds__(256) void k_mt(const float* __restrict__ wq,
                                            const float* __restrict__ bq,
                                            const float* __restrict__ kp,
                                            unsigned short* __restrict__ MT,
                                            float* __restrict__ cst) {
    int h = blockIdx.x >> 5, s = blockIdx.x & 31;
    int c = threadIdx.x;
    const float SC = 0.17677669529663687f;   // 1/sqrt(32)
    if (s < 27) {
        float a = 0.f;
#pragma unroll
        for (int d = 0; d < 32; ++d)
            a += wq[(size_t)c * 256 + h * 32 + d] * kp[(size_t)s * 256 + h * 32 + d];
        MT[((size_t)(h * 32 + s)) * 256 + c] = f2bf(a * SC);
        if (c == 0) {
            float cb = 0.f;
#pragma unroll
            for (int d = 0; d < 32; ++d) cb += bq[h * 32 + d] * kp[(size_t)s * 256 + h * 32 + d];
            cst[h * 32 + s] = cb * SC;
        }
    } else {
        MT[((size_t)(h * 32 + s)) * 256 + c] = 0;
        if (c == 0) cst[h * 32 + s] = -1e30f;
    }
}

// vpT[h][d][s] = bf16(vp[s][h*32+d]) (s>=27 -> 0). grid 8, block 256.
__global__ __launch_bounds__(256) void k_vpt(const float* __restrict__ vp,
                                             unsigned short* __restrict__ vpT) {
    int h = blockIdx.x, t = threadIdx.x;
    int s = t & 31;
#pragma unroll
    for (int i = 0; i < 4; ++i) {
        int d = (t >> 5) + 8 * i;
        vpT[((size_t)(h * 32 + d)) * 32 + s] = (s < 27) ? f2bf(vp[(size_t)s * 256 + h * 32 + d]) : (unsigned short)0;
    }
}

// F0[r][e] = shape_map[r>>5][e]. grid 864, block 256.
__global__ __launch_bounds__(256) void k_finit(const float* __restrict__ sm,
                                               float* __restrict__ F) {
    int r = blockIdx.x, e = threadIdx.x;
    F[(size_t)r * 256 + e] = sm[(size_t)(r >> 5) * 256 + e];
}

// ---------------------------------------------------------------------------
// B1: fused qproj + attention per (b,h). grid 256, block 256 (4 waves).
// scores = (F+qp) @ MT_h + cst_h  (K=256, MFMA); softmax rows; out = P @ vpT_h.
// ---------------------------------------------------------------------------
__global__ __launch_bounds__(256) void b1_attn(const float* __restrict__ F,
                                               const float* __restrict__ qp,
                                               const unsigned short* __restrict__ MT,
                                               const float* __restrict__ cst,
                                               const unsigned short* __restrict__ vpT,
                                               float* __restrict__ aout) {
    __shared__ float S[32][33];
    __shared__ __align__(16) unsigned short Pb[32][40];
    int b = blockIdx.x >> 3, h = blockIdx.x & 7;
    int tid = threadIdx.x, wave = tid >> 6, lane = tid & 63;
    int quad = lane >> 4, l15 = lane & 15;
    int lt = wave >> 1, st = wave & 1;
    const f32x4 z4 = {0.f, 0.f, 0.f, 0.f};
    f32x4 acc = z4;
    int l = lt * 16 + l15;
    bool lok = (l < 27);
    const float* xF = F + (size_t)(l * 32 + b) * 256;
    const float* xq = qp + (size_t)l * 256;
    const unsigned short* Bp = MT + (size_t)(h * 32 + st * 16 + l15) * 256;
#pragma unroll
    for (int kt = 0; kt < 8; ++kt) {
        int c = kt * 32 + quad * 8;
        bf16x8 a;
        if (lok) a = cvt8sum(xF + c, xq + c);
        else {
#pragma unroll
            for (int i = 0; i < 8; ++i) a[i] = 0;
        }
        bf16x8 bb = *(const bf16x8*)(Bp + c);
        acc = __builtin_amdgcn_mfma_f32_16x16x32_bf16(a, bb, acc, 0, 0, 0);
    }
    float cstv = cst[h * 32 + st * 16 + l15];
#pragma unroll
    for (int r = 0; r < 4; ++r) S[lt * 16 + quad * 4 + r][st * 16 + l15] = acc[r] + cstv;
    __syncthreads();
    if (tid < 32) {
        float pv[32];
        float m = -1e30f;
#pragma unroll
        for (int s = 0; s < 32; ++s) { pv[s] = S[tid][s]; m = fmaxf(m, pv[s]); }
        float sum = 0.f;
#pragma unroll
        for (int s = 0; s < 32; ++s) { pv[s] = __expf(pv[s] - m); sum += pv[s]; }
        float inv = 1.f / sum;
#pragma unroll
        for (int s = 0; s < 32; ++s) Pb[tid][s] = f2bf(pv[s] * inv);
    }
    __syncthreads();
    bf16x8 a2 = *(const bf16x8*)&Pb[lt * 16 + l15][quad * 8];
    bf16x8 b2 = *(const bf16x8*)(vpT + (size_t)(h * 32 + st * 16 + l15) * 32 + quad * 8);
    f32x4 o = __builtin_amdgcn_mfma_f32_16x16x32_bf16(a2, b2, z4, 0, 0, 0);
#pragma unroll
    for (int r = 0; r < 4; ++r) {
        int ll = lt * 16 + quad * 4 + r;
        if (ll < 27) aout[(size_t)(ll * 32 + b) * 256 + h * 32 + st * 16 + l15] = o[r];
    }
}

// ---------------------------------------------------------------------------
// B2: fused oproj + LN1 + linear-attn + LN2 for 16-row tile. grid 54, block 256.
// ---------------------------------------------------------------------------
__global__ __launch_bounds__(256) void b2_mid(const float* __restrict__ aout,
                                              const unsigned short* __restrict__ woT,
                                              const float* __restrict__ bo,
                                              float* __restrict__ F,
                                              const float* __restrict__ g1,
                                              const float* __restrict__ b1v,
                                              const float* __restrict__ qp,
                                              const unsigned short* __restrict__ laqT,
                                              const float* __restrict__ labq,
                                              const float* __restrict__ ctx,
                                              const float* __restrict__ g2,
                                              const float* __restrict__ b2v) {
    __shared__ __align__(16) unsigned short X1b[16][264];
    __shared__ float r1s[4][16], r1q[4][16], rm[4][16], rp[4][16], r2s[4][16], r2q[4][16];
    int r0 = blockIdx.x * 16;
    int lrow = r0 >> 5;
    int tid = threadIdx.x, w = tid >> 6, lane = tid & 63;
    int quad = lane >> 4, l15 = lane & 15;
    const f32x4 z4 = {0.f, 0.f, 0.f, 0.f};
    f32x4 acc[4] = {z4, z4, z4, z4};
    const float* Ap = aout + (size_t)(r0 + l15) * 256;
#pragma unroll
    for (int kt = 0; kt < 8; ++kt) {
        int c = kt * 32 + quad * 8;
        bf16x8 a = cvt8(Ap + c);
#pragma unroll
        for (int nt = 0; nt < 4; ++nt) {
            bf16x8 bb = *(const bf16x8*)(woT + (size_t)(w * 64 + nt * 16 + l15) * 256 + c);
            acc[nt] = __builtin_amdgcn_mfma_f32_16x16x32_bf16(a, bb, acc[nt], 0, 0, 0);
        }
    }
    int e_[4];
#pragma unroll
    for (int nt = 0; nt < 4; ++nt) e_[nt] = w * 64 + nt * 16 + l15;
    float val[4][4];
#pragma unroll
    for (int nt = 0; nt < 4; ++nt) {
        float bov = bo[e_[nt]];
#pragma unroll
        for (int r = 0; r < 4; ++r) {
            int row = quad * 4 + r;
            val[nt][r] = acc[nt][r] + bov + F[(size_t)(r0 + row) * 256 + e_[nt]];
        }
    }
    // LN1 reduce
#pragma unroll
    for (int r = 0; r < 4; ++r) {
        float s = val[0][r] + val[1][r] + val[2][r] + val[3][r];
        float q = val[0][r] * val[0][r] + val[1][r] * val[1][r] + val[2][r] * val[2][r] + val[3][r] * val[3][r];
#pragma unroll
        for (int o = 1; o < 16; o <<= 1) { s += __shfl_xor(s, o); q += __shfl_xor(q, o); }
        if (l15 == 0) { r1s[w][quad * 4 + r] = s; r1q[w][quad * 4 + r] = q; }
    }
    __syncthreads();
#pragma unroll
    for (int r = 0; r < 4; ++r) {
        int row = quad * 4 + r;
        float S = r1s[0][row] + r1s[1][row] + r1s[2][row] + r1s[3][row];
        float Q = r1q[0][row] + r1q[1][row] + r1q[2][row] + r1q[3][row];
        float mean = S * (1.f / 256.f);
        float var  = Q * (1.f / 256.f) - mean * mean;
        float rs   = rsqrtf(var + EPS_);
#pragma unroll
        for (int nt = 0; nt < 4; ++nt) {
            int e = e_[nt];
            float f1 = (val[nt][r] - mean) * rs * g1[e] + b1v[e];
            X1b[row][e] = f2bf(f1 + qp[(size_t)lrow * 256 + e]);
            val[nt][r] = f1;   // keep F1 in regs for residual
        }
    }
    __syncthreads();
    // GEMM2: (F1+qp) @ la_wq
    f32x4 acc2[4] = {z4, z4, z4, z4};
#pragma unroll
    for (int kt = 0; kt < 8; ++kt) {
        int c = kt * 32 + quad * 8;
        bf16x8 a = *(const bf16x8*)&X1b[l15][c];
#pragma unroll
        for (int nt = 0; nt < 4; ++nt) {
            bf16x8 bb = *(const bf16x8*)(laqT + (size_t)(w * 64 + nt * 16 + l15) * 256 + c);
            acc2[nt] = __builtin_amdgcn_mfma_f32_16x16x32_bf16(a, bb, acc2[nt], 0, 0, 0);
        }
    }
    float y[4][4];
#pragma unroll
    for (int nt = 0; nt < 4; ++nt) {
        float bqv = labq[e_[nt]];
#pragma unroll
        for (int r = 0; r < 4; ++r) y[nt][r] = (acc2[nt][r] + bqv) * 0.0625f;
    }
    // softmax over e per row: max
#pragma unroll
    for (int r = 0; r < 4; ++r) {
        float m = fmaxf(fmaxf(y[0][r], y[1][r]), fmaxf(y[2][r], y[3][r]));
#pragma unroll
        for (int o = 1; o < 16; o <<= 1) m = fmaxf(m, __shfl_xor(m, o));
        if (l15 == 0) rm[w][quad * 4 + r] = m;
    }
    __syncthreads();
    float p[4][4];
#pragma unroll
    for (int r = 0; r < 4; ++r) {
        int row = quad * 4 + r;
        float M = fmaxf(fmaxf(rm[0][row], rm[1][row]), fmaxf(rm[2][row], rm[3][row]));
        float ps = 0.f;
#pragma unroll
        for (int nt = 0; nt < 4; ++nt) { p[nt][r] = __expf(y[nt][r] - M); ps += p[nt][r]; }
#pragma unroll
        for (int o = 1; o < 16; o <<= 1) ps += __shfl_xor(ps, o);
        if (l15 == 0) rp[w][row] = ps;
    }
    __syncthreads();
#pragma unroll
    for (int r = 0; r < 4; ++r) {
        int row = quad * 4 + r;
        float Ssum = rp[0][row] + rp[1][row] + rp[2][row] + rp[3][row];
        float inv = 1.f / Ssum;
#pragma unroll
        for (int nt = 0; nt < 4; ++nt)
            val[nt][r] = val[nt][r] + (p[nt][r] * inv) * ctx[e_[nt]];
    }
    // LN2
#pragma unroll
    for (int r = 0; r < 4; ++r) {
        float s = val[0][r] + val[1][r] + val[2][r] + val[3][r];
        float q = val[0][r] * val[0][r] + val[1][r] * val[1][r] + val[2][r] * val[2][r] + val[3][r] * val[3][r];
#pragma unroll
        for (int o = 1; o < 16; o <<= 1) { s += __shfl_xor(s, o); q += __shfl_xor(q, o); }
        if (l15 == 0) { r2s[w][quad * 4 + r] = s; r2q[w][quad * 4 + r] = q; }
    }
    __syncthreads();
#pragma unroll
    for (int r = 0; r < 4; ++r) {
        int row = quad * 4 + r;
        float S = r2s[0][row] + r2s[1][row] + r2s[2][row] + r2s[3][row];
        float Q = r2q[0][row] + r2q[1][row] + r2q[2][row] + r2q[3][row];
        float mean = S * (1.f / 256.f);
        float var  = Q * (1.f / 256.f) - mean * mean;
        float rs   = rsqrtf(var + EPS_);
#pragma unroll
        for (int nt = 0; nt < 4; ++nt) {
            int e = e_[nt];
            F[(size_t)(r0 + row) * 256 + e] = (val[nt][r] - mean) * rs * g2[e] + b2v[e];
        }
    }
}

// ---------------------------------------------------------------------------
// B3: FFN1 H = gelu(F @ w1 + b1), bf16 out. grid 1728 (54 m x 32 n), block 256.
// ---------------------------------------------------------------------------
__global__ __launch_bounds__(256) void b3_ffn1(const float* __restrict__ F,
                                               const unsigned short* __restrict__ w1T,
                                               const float* __restrict__ fb1,
                                               unsigned short* __restrict__ Hb) {
    int bm = blockIdx.x >> 5, bn = blockIdx.x & 31;
    int tid = threadIdx.x, w = tid >> 6, lane = tid & 63;
    int quad = lane >> 4, l15 = lane & 15;
    int r0 = bm * 16;
    int n0 = bn * 64 + w * 16;
    const f32x4 z4 = {0.f, 0.f, 0.f, 0.f};
    f32x4 acc = z4;
    const float* Ap = F + (size_t)(r0 + l15) * 256;
    const unsigned short* Bp = w1T + (size_t)(n0 + l15) * 256;
#pragma unroll
    for (int kt = 0; kt < 8; ++kt) {
        int c = kt * 32 + quad * 8;
        bf16x8 a = cvt8(Ap + c);
        bf16x8 bb = *(const bf16x8*)(Bp + c);
        acc = __builtin_amdgcn_mfma_f32_16x16x32_bf16(a, bb, acc, 0, 0, 0);
    }
    int e = n0 + l15;
    float bv = fb1[e];
#pragma unroll
    for (int r = 0; r < 4; ++r) {
        float hh = acc[r] + bv;
        float g = 0.5f * hh * (1.f + erff(hh * 0.70710678118654752f));
        Hb[(size_t)(r0 + quad * 4 + r) * 2048 + e] = f2bf(g);
    }
}

// ---------------------------------------------------------------------------
// B4: FFN2 + bias + residual + LN3 + output write. grid 54, block 256.
// ---------------------------------------------------------------------------
__global__ __launch_bounds__(256) void b4_ffn2(const unsigned short* __restrict__ Hb,
                                               const unsigned short* __restrict__ w2T,
                                               const float* __restrict__ fb2,
                                               float* __restrict__ F,
                                               const float* __restrict__ g3,
                                               const float* __restrict__ b3v,
                                               float* __restrict__ out,
                                               int step) {
    __shared__ float r3s[4][16], r3q[4][16];
    int r0 = blockIdx.x * 16;
    int tid = threadIdx.x, w = tid >> 6, lane = tid & 63;
    int quad = lane >> 4, l15 = lane & 15;
    const f32x4 z4 = {0.f, 0.f, 0.f, 0.f};
    f32x4 acc[4] = {z4, z4, z4, z4};
    const unsigned short* Ap = Hb + (size_t)(r0 + l15) * 2048;
#pragma unroll 4
    for (int kt = 0; kt < 64; ++kt) {
        int c = kt * 32 + quad * 8;
        bf16x8 a = *(const bf16x8*)(Ap + c);
#pragma unroll
        for (int nt = 0; nt < 4; ++nt) {
            bf16x8 bb = *(const bf16x8*)(w2T + (size_t)(w * 64 + nt * 16 + l15) * 2048 + c);
            acc[nt] = __builtin_amdgcn_mfma_f32_16x16x32_bf16(a, bb, acc[nt], 0, 0, 0);
        }
    }
    int e_[4];
#pragma unroll
    for (int nt = 0; nt < 4; ++nt) e_[nt] = w * 64 + nt * 16 + l15;
    float val[4][4];
#pragma unroll
    for (int nt = 0; nt < 4; ++nt) {
        float bv = fb2[e_[nt]];
#pragma unroll
        for (int r = 0; r < 4; ++r) {
            int row = quad * 4 + r;
            val[nt][r] = acc[nt][r] + bv + F[(size_t)(r0 + row) * 256 + e_[nt]];
        }
    }
#pragma unroll
    for (int r = 0; r < 4; ++r) {
        float s = val[0][r] + val[1][r] + val[2][r] + val[3][r];
        float q = val[0][r] * val[0][r] + val[1][r] * val[1][r] + val[2][r] * val[2][r] + val[3][r] * val[3][r];
#pragma unroll
        for (int o = 1; o < 16; o <<= 1) { s += __shfl_xor(s, o); q += __shfl_xor(q, o); }
        if (l15 == 0) { r3s[w][quad * 4 + r] = s; r3q[w][quad * 4 + r] = q; }
    }
    __syncthreads();
#pragma unroll
    for (int r = 0; r < 4; ++r) {
        int row = quad * 4 + r;
        float S = r3s[0][row] + r3s[1][row] + r3s[2][row] + r3s[3][row];
        float Q = r3q[0][row] + r3q[1][row] + r3q[2][row] + r3q[3][row];
        float mean = S * (1.f / 256.f);
        float var  = Q * (1.f / 256.f) - mean * mean;
        float rs   = rsqrtf(var + EPS_);
#pragma unroll
        for (int nt = 0; nt < 4; ++nt) {
            int e = e_[nt];
            float o = (val[nt][r] - mean) * rs * g3[e] + b3v[e];
            F[(size_t)(r0 + row) * 256 + e] = o;
            out[(size_t)step * 221184 + (size_t)(r0 + row) * 256 + e] = o;
        }
    }
}

// ---------------------------------------------------------------------------
extern "C" void kernel_launch(void* const* d_in, const int* in_sizes, int n_in,
                              void* d_out, int out_size, void* d_ws, size_t ws_size,
                              hipStream_t stream) {
    const float* f_e     = (const float*)d_in[0];
    const float* pos_emb = (const float*)d_in[1];
    const float* sm      = (const float*)d_in[3];
    const float* mha_wq  = (const float*)d_in[4];
    const float* mha_bq  = (const float*)d_in[5];
    const float* mha_wk  = (const float*)d_in[6];
    const float* mha_bk  = (const float*)d_in[7];
    const float* mha_wv  = (const float*)d_in[8];
    const float* mha_bv  = (const float*)d_in[9];
    const float* mha_wo  = (const float*)d_in[10];
    const float* mha_bo  = (const float*)d_in[11];
    const float* la_wq   = (const float*)d_in[12];
    const float* la_bq   = (const float*)d_in[13];
    const float* la_wk   = (const float*)d_in[14];
    const float* la_bk   = (const float*)d_in[15];
    const float* la_wv   = (const float*)d_in[16];
    const float* la_bv   = (const float*)d_in[17];
    const float* ff_w1   = (const float*)d_in[18];
    const float* ff_b1   = (const float*)d_in[19];
    const float* ff_w2   = (const float*)d_in[20];
    const float* ff_b2   = (const float*)d_in[21];
    const float* n1_g    = (const float*)d_in[22];
    const float* n1_b    = (const float*)d_in[23];
    const float* n2_g    = (const float*)d_in[24];
    const float* n2_b    = (const float*)d_in[25];
    const float* n3_g    = (const float*)d_in[26];
    const float* n3_b    = (const float*)d_in[27];

    float* ws = (float*)d_ws;
    float* part = ws + WS_PART;
    float* ctx  = ws + WS_CTX;
    float* qp   = ws + WS_QP;
    float* kp   = ws + WS_KP;
    float* vp   = ws + WS_VP;
    float* F    = ws + WS_F;
    float* aout = ws + WS_ATTN;
    unsigned short* Hb   = (unsigned short*)(ws + WS_H);
    unsigned short* wkb  = (unsigned short*)(ws + WS_WKB);
    unsigned short* wvb  = (unsigned short*)(ws + WS_WVB);
    unsigned short* woT  = (unsigned short*)(ws + WS_WOT);
    unsigned short* laqT = (unsigned short*)(ws + WS_LAQT);
    unsigned short* w1T  = (unsigned short*)(ws + WS_W1T);
    unsigned short* w2T  = (unsigned short*)(ws + WS_W2T);
    unsigned short* MT   = (unsigned short*)(ws + WS_MT);
    unsigned short* vpT  = (unsigned short*)(ws + WS_VPT);
    float* cst = ws + WS_CST;

    float* out = (float*)d_out;

    // setup
    k_trans<<<3328, 256, 0, stream>>>(la_wk, la_wv, mha_wo, la_wq, ff_w1, ff_w2,
                                      wkb, wvb, woT, laqT, w1T, w2T);
    k_qpos<<<27, 256, 0, stream>>>(qp);
    k_kvproj<<<54, 256, 0, stream>>>(sm, mha_wk, mha_bk, mha_wv, mha_bv, kp, vp);
    k_mt<<<256, 256, 0, stream>>>(mha_wq, mha_bq, kp, MT, cst);
    k_vpt<<<8, 256, 0, stream>>>(vp, vpT);
    k_finit<<<864, 256, 0, stream>>>(sm, F);

    // phase A
    pa_gemm<<<2048, 256, 0, stream>>>(f_e, pos_emb, wkb, wvb, la_bk, la_bv, part);
    pa_reduce<<<256, 256, 0, stream>>>(part, ctx);

    // phase B: 3 decoder steps
    for (int s = 0; s < 3; ++s) {
        b1_attn<<<256, 256, 0, stream>>>(F, qp, MT, cst, vpT, aout);
        b2_mid<<<54, 256, 0, stream>>>(aout, woT, mha_bo, F, n1_g, n1_b, qp,
                                       laqT, la_bq, ctx, n2_g, n2_b);
        b3_ffn1<<<1728, 256, 0, stream>>>(F, w1T, ff_b1, Hb);
        b4_ffn2<<<54, 256, 0, stream>>>(Hb, w2T, ff_b2, F, n3_g, n3_b, out, s);
    }
}